// Round 2
// 616.927 us; speedup vs baseline: 1.5863x; 1.5863x over previous
//
#include <hip/hip_runtime.h>

// ConvTranspose4d, stride 2: x[4,64,12^4] (*) w[64,64,3^4] -> out[4,64,25^4]
// R2: merged-parity-class block + dense LDS epilogue (kills the 6.4x write
// amplification seen in R0), restructured to fit STATIC 56KB LDS (R1's 111KB
// dynamic-LDS + hipFuncSetAttribute path is the suspected container killer).
//
// Block = (b,p1,p2); 512 thr / 8 waves; wave-pair (w>>1) owns parity class (r3,r4).
// Weight taps staged in 3 groups by k3 (ws[3][64][72]); group g is computed by the
// two classes with r3 == (g&1). xs staged once per (k1,k2) combo, reused by groups.
// Epilogue assembles dense out rows in stg[16][625] f32 (overlays xs/ws) -> full-line
// coalesced stores, no L2 read-modify-write.

typedef short bf16x8 __attribute__((ext_vector_type(8)));
typedef float f32x4 __attribute__((ext_vector_type(4)));

__device__ __forceinline__ unsigned short f2bf(float f) {
    unsigned int u = __float_as_uint(f);
    u = (u + 0x7FFFu + ((u >> 16) & 1u)) >> 16;
    return (unsigned short)u;
}

// w[ci][co][kk(81)] fp32 -> wt[kk][co][ci] bf16
__global__ __launch_bounds__(256) void wtrans_kernel(const float* __restrict__ w,
                                                     unsigned short* __restrict__ wt) {
    int tid = blockIdx.x * 256 + threadIdx.x;
    if (tid >= 81 * 64 * 64) return;
    int ci = tid & 63;
    int co = (tid >> 6) & 63;
    int kk = tid >> 12;
    wt[tid] = f2bf(w[(ci * 64 + co) * 81 + kk]);
}

#define XS_BYTES 28224          // [196][72] u16
#define WS_BYTES 27648          // [3][64][72] u16
#define SMEM_BYTES 57344        // >= XS+WS (55872), >= stg[16][625] f32 (40000)

__global__ __launch_bounds__(512, 2) void convt_mfma_kernel(
        const float* __restrict__ x,
        const unsigned short* __restrict__ wt,
        const float* __restrict__ bias,
        float* __restrict__ out) {

    __shared__ __align__(16) char smem[SMEM_BYTES];
    unsigned short (*xs)[72]     = (unsigned short (*)[72])smem;
    unsigned short (*ws)[64][72] = (unsigned short (*)[64][72])(smem + XS_BYTES);
    float (*stg)[625]            = (float (*)[625])smem;   // epilogue overlay

    // bijective XCD-chunk swizzle: 2500 wgs on 8 XCDs (q=312, r=4) so p2-neighbor
    // blocks (sharing output-boundary cache lines) land on the same XCD.
    int orig = blockIdx.x;
    int xcd = orig & 7, oj = orig >> 3;
    int wg = (xcd < 4 ? xcd * 313 : 1252 + (xcd - 4) * 312) + oj;
    int p2 = wg % 25; int tq = wg / 25;
    int p1 = tq % 25; int b = tq / 25;

    // valid (k,i) taps for dims 1,2 at (p1,p2)
    int i1v[2], k1v[2], n1 = 0;
    { int h = p1 >> 1, q = p1 & 1;
      for (int s = 0; s < 2 - q; ++s) { int i = h - s; if (0 <= i && i < 12) { i1v[n1] = i; k1v[n1] = 2 * s + q; ++n1; } } }
    int i2v[2], k2v[2], n2 = 0;
    { int h = p2 >> 1, q = p2 & 1;
      for (int s = 0; s < 2 - q; ++s) { int i = h - s; if (0 <= i && i < 12) { i2v[n2] = i; k2v[n2] = 2 * s + q; ++n2; } } }
    int ncomb = n1 * n2;

    int tid = threadIdx.x;
    int lane = tid & 63, wave = tid >> 6;
    int n_lo = lane & 15, quad = lane >> 4;

    // wave-pair <-> parity class (r3,r4); this wave computes tiles hw, hw+2, hw+4, ...
    int cls = wave >> 1, hw = wave & 1;
    int r3 = cls >> 1, r4 = cls & 1;
    int n4 = 13 - r4;
    int N = (13 - r3) * n4;
    int ntiles = (N + 15) >> 4;          // 11 / 10 / 10 / 9
    int nt4 = 2 - r4;

    int nmyt = 0; int pe3a[6], pe4a[6], posa[6];
    #pragma unroll
    for (int j = 0; j < 6; ++j) {
        int t = hw + 2 * j;
        if (t < ntiles) {
            int pos = t * 16 + n_lo;
            int cp = pos < N ? pos : N - 1;
            pe3a[j] = cp / n4; pe4a[j] = cp - pe3a[j] * n4; posa[j] = pos;
            nmyt = j + 1;
        }
    }

    // zero xs once (halo rows/cols stay zero; interior rewritten per combo)
    for (int f = tid; f < XS_BYTES / 4; f += 512) ((int*)smem)[f] = 0;

    // seed accumulators with bias (each output element maps to exactly one acc slot)
    f32x4 acc[6][4];
    #pragma unroll
    for (int mt = 0; mt < 4; ++mt) {
        #pragma unroll
        for (int rg = 0; rg < 4; ++rg) {
            float bv = bias[mt * 16 + quad * 4 + rg];
            #pragma unroll
            for (int j = 0; j < 6; ++j) acc[j][mt][rg] = bv;
        }
    }
    __syncthreads();

    for (int c = 0; c < ncomb; ++c) {
        if (c) __syncthreads();          // prev combo's compute done with xs/ws
        int c1 = c / n2, c2 = c - (c / n2) * n2;
        int i1 = i1v[c1], k1 = k1v[c1];
        int i2 = i2v[c2], k2 = k2v[c2];

        // stage x slab: x[b, ci, i1, i2, :, :] -> xs[(i3+1)*14+(i4+1)][ci] bf16
        const float* xb = x + (size_t)b * 64 * 20736 + i1 * 1728 + i2 * 144;
        for (int it = 0; it < 5; ++it) {
            int f = it * 512 + tid;
            if (f < 2304) {                       // 64 ci * 36 float4-chunks
                int ci = f / 36, cc = f - 36 * ci;
                float4 v = *(const float4*)(xb + (size_t)ci * 20736 + cc * 4);
                #pragma unroll
                for (int u = 0; u < 4; ++u) {
                    int e = cc * 4 + u;
                    int a3 = e / 12, a4 = e - a3 * 12;
                    xs[(a3 + 1) * 14 + (a4 + 1)][ci] = f2bf(((const float*)&v)[u]);
                }
            }
        }

        int kb9 = (k1 * 3 + k2) * 9;
        for (int g = 0; g < 3; ++g) {
            if (g) __syncthreads();      // group g-1 compute done reading ws
            // stage taps (k3=g, k4=0..2): wt[kb9+3g .. +3) -> ws[k4][co][ci]
            const bf16x8* wsrc = (const bf16x8*)(wt + (size_t)(kb9 + 3 * g) * 4096);
            #pragma unroll
            for (int it = 0; it < 3; ++it) {
                int idx = it * 512 + tid;          // 3*512 bf16x8 chunks
                int tp = idx >> 9, rch = idx & 511;
                *(bf16x8*)&ws[tp][rch >> 3][(rch & 7) << 3] = wsrc[idx];
            }
            __syncthreads();

            // classes with r3 == (g&1) compute tap row k3=g (s3 = (g-r3)/2)
            if ((g & 1) == r3) {
                int s3 = (g - r3) >> 1;
                for (int s4 = 0; s4 < nt4; ++s4) {
                    int k4 = 2 * s4 + r4;
                    #pragma unroll
                    for (int kc = 0; kc < 2; ++kc) {
                        int kof = kc * 32 + quad * 8;
                        bf16x8 a0  = *(const bf16x8*)&ws[k4][n_lo     ][kof];
                        bf16x8 a1  = *(const bf16x8*)&ws[k4][n_lo + 16][kof];
                        bf16x8 a2  = *(const bf16x8*)&ws[k4][n_lo + 32][kof];
                        bf16x8 a3v = *(const bf16x8*)&ws[k4][n_lo + 48][kof];
                        #pragma unroll
                        for (int j = 0; j < 6; ++j) {
                            if (j < nmyt) {
                                int row = (pe3a[j] - s3 + 1) * 14 + (pe4a[j] - s4 + 1);
                                bf16x8 bb = *(const bf16x8*)&xs[row][kof];
                                acc[j][0] = __builtin_amdgcn_mfma_f32_16x16x32_bf16(a0,  bb, acc[j][0], 0, 0, 0);
                                acc[j][1] = __builtin_amdgcn_mfma_f32_16x16x32_bf16(a1,  bb, acc[j][1], 0, 0, 0);
                                acc[j][2] = __builtin_amdgcn_mfma_f32_16x16x32_bf16(a2,  bb, acc[j][2], 0, 0, 0);
                                acc[j][3] = __builtin_amdgcn_mfma_f32_16x16x32_bf16(a3v, bb, acc[j][3], 0, 0, 0);
                            }
                        }
                    }
                }
            }
        }
    }

    __syncthreads();   // xs/ws dead from here; stg overlays them

    // epilogue: 4 co-chunks of 16; deposit all 4 classes into stg[16][625], then
    // stream out dense (consecutive threads -> consecutive addresses -> full lines).
    size_t obase = (size_t)b * 64 * 390625 + (size_t)(p1 * 25 + p2) * 625;
    #pragma unroll
    for (int ch = 0; ch < 4; ++ch) {
        #pragma unroll
        for (int j = 0; j < 6; ++j) {
            if (j < nmyt && posa[j] < N) {
                int p34 = (2 * pe3a[j] + r3) * 25 + (2 * pe4a[j] + r4);
                #pragma unroll
                for (int rg = 0; rg < 4; ++rg)
                    stg[quad * 4 + rg][p34] = acc[j][ch][rg];
            }
        }
        __syncthreads();
        for (int idx = tid; idx < 10000; idx += 512) {   // 16 co * 625 pos
            int co_l = idx / 625, e = idx - 625 * co_l;
            out[obase + (size_t)(ch * 16 + co_l) * 390625 + e] = stg[co_l][e];
        }
        __syncthreads();
    }
}

extern "C" void kernel_launch(void* const* d_in, const int* in_sizes, int n_in,
                              void* d_out, int out_size, void* d_ws, size_t ws_size,
                              hipStream_t stream) {
    const float* x    = (const float*)d_in[0];
    const float* w    = (const float*)d_in[1];
    const float* bias = (const float*)d_in[2];
    float* out = (float*)d_out;
    unsigned short* wt = (unsigned short*)d_ws;   // 81*64*64*2 = 663 KB scratch

    wtrans_kernel<<<(81 * 64 * 64 + 255) / 256, 256, 0, stream>>>(w, wt);
    convt_mfma_kernel<<<2500, 512, 0, stream>>>(x, wt, bias, out);
}